// Round 4
// baseline (327.003 us; speedup 1.0000x reference)
//
#include <hip/hip_runtime.h>
#include <hip/hip_bf16.h>

#define BR_N     1000000
#define DIM      128
#define TILE_M   64
#define NTILES   (BR_N / TILE_M)   /* 15625, exact */
#define NTHREADS 512
#define NBLOCKS  1024

typedef __attribute__((ext_vector_type(8))) short    bf16x8;
typedef __attribute__((ext_vector_type(4))) float    f32x4;
typedef __attribute__((ext_vector_type(4))) unsigned u32x4;
typedef __attribute__((ext_vector_type(2))) unsigned u32x2;

// f32 pair -> packed bf16x2 (RNE) via v_cvt_pk_bf16_f32
static __device__ __forceinline__ unsigned pk2(float a, float b) {
    union { __hip_bfloat162 h; unsigned u; } v;
    v.h = __float22bfloat162_rn(float2{a, b});
    return v.u;
}

union FragU { bf16x8 v; u32x4 u; };

static __device__ __forceinline__ bf16x8 cvt8(const f32x4 a, const f32x4 b) {
    FragU r;
    r.u.x = pk2(a.x, a.y);
    r.u.y = pk2(a.z, a.w);
    r.u.z = pk2(b.x, b.y);
    r.u.w = pk2(b.z, b.w);
    return r.v;
}

static __device__ __forceinline__ float bf2f(unsigned short b) {
    union { unsigned u; float f; } v;
    v.u = ((unsigned)b) << 16;
    return v.f;
}

// out = sigmoid(s@Vs.T + o@Vo.T) * relu(s@Ws.T + o@Wo.T + s*(o.w))
//
// Operand-swapped MFMA: acc = mfma(W_frag /*A*/, x_frag /*B*/) so
// D[i=feature][j=batch-row]; each lane holds 4 CONSECUTIVE features of one
// row -> dwordx4 epilogue store + 8B sval LDS read. Fragment register data
// is identical to the unswapped version (A/B lane layouts are symmetric).
//
// launch_bounds(512,2): VGPR cap 128 — weights(64) + prefetch(32) + working
// fits WITHOUT scratch spill ((512,4) spilled: +1.25 GB HBM, R2).
__global__ __launch_bounds__(NTHREADS, 2)
void relup_kernel(const float* __restrict__ S, const float* __restrict__ O,
                  const float* __restrict__ Vs, const float* __restrict__ Vo,
                  const float* __restrict__ Ws, const float* __restrict__ Wo,
                  const float* __restrict__ W1, float* __restrict__ out)
{
    // double-buffered bf16 tiles, row stride 256 B, byte-swizzled:
    // 16B granule g of row r lives at (g ^ (r&7))
    __shared__ __align__(16) unsigned char sT[2][TILE_M * 256];
    __shared__ __align__(16) unsigned char oT[2][TILE_M * 256];
    __shared__ float dotv[2][TILE_M];

    const int tid  = threadIdx.x;
    const int lane = tid & 63;
    const int wv   = tid >> 6;       // wave id 0..7, owns output features [wv*16, wv*16+16)
    const int c0   = wv << 4;

    // ---- preload weight fragments into registers (held for whole kernel) ----
    // lane holds W[c0+(lane&15)][kk*32 + (lane>>4)*8 + j] — used as MFMA A operand
    bf16x8 fVs[4], fVo[4], fWs[4], fWo[4];
    {
        const int wr = c0 + (lane & 15);
        const int wc = (lane >> 4) << 3;
        #pragma unroll
        for (int kk = 0; kk < 4; ++kk) {
            const int off = wr * DIM + kk * 32 + wc;
            fVs[kk] = cvt8(*(const f32x4*)(Vs + off), *(const f32x4*)(Vs + off + 4));
            fVo[kk] = cvt8(*(const f32x4*)(Vo + off), *(const f32x4*)(Vo + off + 4));
            fWs[kk] = cvt8(*(const f32x4*)(Ws + off), *(const f32x4*)(Ws + off + 4));
            fWo[kk] = cvt8(*(const f32x4*)(Wo + off), *(const f32x4*)(Wo + off + 4));
        }
    }

    // staging assignment: thread -> (row 0..63, 16-float segment 0..7)
    const int str = tid >> 3;
    const int seg = tid & 7;
    const int swS = (str & 7) << 4;
    const int sb0 = str * 256 + ((seg * 32) ^ swS);
    const int sb1 = str * 256 + (((seg * 32) + 16) ^ swS);
    const float* wp = W1 + seg * 16;   // reloaded per tile (L2-hot) to save 16 VGPRs

    int t   = blockIdx.x;
    int cur = 0;

    // ---- prefetch first tile into registers ----
    f32x4 Ps0, Ps1, Ps2, Ps3, Po0, Po1, Po2, Po3;
    {
        const float* sp = S + (t * TILE_M + str) * DIM + seg * 16;
        const float* op = O + (t * TILE_M + str) * DIM + seg * 16;
        Ps0 = ((const f32x4*)sp)[0]; Ps1 = ((const f32x4*)sp)[1];
        Ps2 = ((const f32x4*)sp)[2]; Ps3 = ((const f32x4*)sp)[3];
        Po0 = ((const f32x4*)op)[0]; Po1 = ((const f32x4*)op)[1];
        Po2 = ((const f32x4*)op)[2]; Po3 = ((const f32x4*)op)[3];
    }
    // ---- pack first tile -> buf0, dot -> dotv[0] ----
    {
        const f32x4 w0 = ((const f32x4*)wp)[0], w1 = ((const f32x4*)wp)[1];
        const f32x4 w2 = ((const f32x4*)wp)[2], w3 = ((const f32x4*)wp)[3];
        float p = Po0.x*w0.x + Po0.y*w0.y + Po0.z*w0.z + Po0.w*w0.w
                + Po1.x*w1.x + Po1.y*w1.y + Po1.z*w1.z + Po1.w*w1.w
                + Po2.x*w2.x + Po2.y*w2.y + Po2.z*w2.z + Po2.w*w2.w
                + Po3.x*w3.x + Po3.y*w3.y + Po3.z*w3.z + Po3.w*w3.w;
        u32x4 pa = { pk2(Ps0.x,Ps0.y), pk2(Ps0.z,Ps0.w), pk2(Ps1.x,Ps1.y), pk2(Ps1.z,Ps1.w) };
        u32x4 pb = { pk2(Ps2.x,Ps2.y), pk2(Ps2.z,Ps2.w), pk2(Ps3.x,Ps3.y), pk2(Ps3.z,Ps3.w) };
        u32x4 pc = { pk2(Po0.x,Po0.y), pk2(Po0.z,Po0.w), pk2(Po1.x,Po1.y), pk2(Po1.z,Po1.w) };
        u32x4 pd = { pk2(Po2.x,Po2.y), pk2(Po2.z,Po2.w), pk2(Po3.x,Po3.y), pk2(Po3.z,Po3.w) };
        *(u32x4*)(sT[0] + sb0) = pa;
        *(u32x4*)(sT[0] + sb1) = pb;
        *(u32x4*)(oT[0] + sb0) = pc;
        *(u32x4*)(oT[0] + sb1) = pd;
        p += __shfl_xor(p, 1);
        p += __shfl_xor(p, 2);
        p += __shfl_xor(p, 4);
        if (seg == 0) dotv[0][str] = p;
    }
    __syncthreads();

    while (t < NTILES) {
        const int row0 = t * TILE_M;
        const int tn   = t + (int)gridDim.x;
        const int tp   = (tn < NTILES) ? tn : t;   // clamp: harmless L2-hot reload on last iter
        const int nxt  = cur ^ 1;

        // ---- issue next tile's loads first: latency hides under MFMA phase ----
        {
            const float* sp = S + (tp * TILE_M + str) * DIM + seg * 16;
            const float* op = O + (tp * TILE_M + str) * DIM + seg * 16;
            Ps0 = ((const f32x4*)sp)[0]; Ps1 = ((const f32x4*)sp)[1];
            Ps2 = ((const f32x4*)sp)[2]; Ps3 = ((const f32x4*)sp)[3];
            Po0 = ((const f32x4*)op)[0]; Po1 = ((const f32x4*)op)[1];
            Po2 = ((const f32x4*)op)[2]; Po3 = ((const f32x4*)op)[3];
        }

        // ---- MFMA + epilogue for tile t (reads buf[cur]) ----
        const unsigned char* sTc = sT[cur];
        const unsigned char* oTc = oT[cur];
        #pragma unroll
        for (int b = 0; b < 4; ++b) {
            const int r0  = b << 4;
            const int ar  = r0 + (lane & 15);
            const int swA = (ar & 7) << 4;
            const int acb = (lane >> 4) << 4;
            bf16x8 fs[4], fo[4];
            #pragma unroll
            for (int kk = 0; kk < 4; ++kk) {
                const int cb = ((kk << 6) + acb) ^ swA;
                fs[kk] = *(const bf16x8*)(sTc + ar * 256 + cb);
                fo[kk] = *(const bf16x8*)(oTc + ar * 256 + cb);
            }
            f32x4 accg = {0.f, 0.f, 0.f, 0.f};
            f32x4 accd = {0.f, 0.f, 0.f, 0.f};
            #pragma unroll
            for (int kk = 0; kk < 4; ++kk) {
                accg = __builtin_amdgcn_mfma_f32_16x16x32_bf16(fVs[kk], fs[kk], accg, 0, 0, 0);
                accg = __builtin_amdgcn_mfma_f32_16x16x32_bf16(fVo[kk], fo[kk], accg, 0, 0, 0);
                accd = __builtin_amdgcn_mfma_f32_16x16x32_bf16(fWs[kk], fs[kk], accd, 0, 0, 0);
                accd = __builtin_amdgcn_mfma_f32_16x16x32_bf16(fWo[kk], fo[kk], accd, 0, 0, 0);
            }
            // swapped C/D layout: lane -> batch row r0+(lane&15),
            // features f0..f0+3 where f0 = c0 + (lane>>4)*4, reg r = feature f0+r
            const int row = r0 + (lane & 15);
            const int f0  = c0 + ((lane >> 4) << 2);
            const float dv = dotv[cur][row];
            const int sOff = row * 256 + ((2 * f0) ^ ((row & 7) << 4));
            const u32x2 sv = *(const u32x2*)(sTc + sOff);   // 4 bf16 of s
            const float sq0 = bf2f((unsigned short)(sv.x & 0xffffu));
            const float sq1 = bf2f((unsigned short)(sv.x >> 16));
            const float sq2 = bf2f((unsigned short)(sv.y & 0xffffu));
            const float sq3 = bf2f((unsigned short)(sv.y >> 16));
            f32x4 res;
            {
                const float g0 = 1.0f / (1.0f + __expf(-accg[0]));
                const float g1 = 1.0f / (1.0f + __expf(-accg[1]));
                const float g2 = 1.0f / (1.0f + __expf(-accg[2]));
                const float g3 = 1.0f / (1.0f + __expf(-accg[3]));
                float d0 = accd[0] + sq0 * dv; d0 = d0 > 0.f ? d0 : 0.f;
                float d1 = accd[1] + sq1 * dv; d1 = d1 > 0.f ? d1 : 0.f;
                float d2 = accd[2] + sq2 * dv; d2 = d2 > 0.f ? d2 : 0.f;
                float d3 = accd[3] + sq3 * dv; d3 = d3 > 0.f ? d3 : 0.f;
                res.x = g0 * d0; res.y = g1 * d1; res.z = g2 * d2; res.w = g3 * d3;
            }
            *(f32x4*)(out + (row0 + row) * DIM + f0) = res;
        }

        // ---- pack next tile -> buf[nxt], dot -> dotv[nxt] ----
        {
            const f32x4 w0 = ((const f32x4*)wp)[0], w1 = ((const f32x4*)wp)[1];
            const f32x4 w2 = ((const f32x4*)wp)[2], w3 = ((const f32x4*)wp)[3];
            float p = Po0.x*w0.x + Po0.y*w0.y + Po0.z*w0.z + Po0.w*w0.w
                    + Po1.x*w1.x + Po1.y*w1.y + Po1.z*w1.z + Po1.w*w1.w
                    + Po2.x*w2.x + Po2.y*w2.y + Po2.z*w2.z + Po2.w*w2.w
                    + Po3.x*w3.x + Po3.y*w3.y + Po3.z*w3.z + Po3.w*w3.w;
            u32x4 pa = { pk2(Ps0.x,Ps0.y), pk2(Ps0.z,Ps0.w), pk2(Ps1.x,Ps1.y), pk2(Ps1.z,Ps1.w) };
            u32x4 pb = { pk2(Ps2.x,Ps2.y), pk2(Ps2.z,Ps2.w), pk2(Ps3.x,Ps3.y), pk2(Ps3.z,Ps3.w) };
            u32x4 pc = { pk2(Po0.x,Po0.y), pk2(Po0.z,Po0.w), pk2(Po1.x,Po1.y), pk2(Po1.z,Po1.w) };
            u32x4 pd = { pk2(Po2.x,Po2.y), pk2(Po2.z,Po2.w), pk2(Po3.x,Po3.y), pk2(Po3.z,Po3.w) };
            *(u32x4*)(sT[nxt] + sb0) = pa;
            *(u32x4*)(sT[nxt] + sb1) = pb;
            *(u32x4*)(oT[nxt] + sb0) = pc;
            *(u32x4*)(oT[nxt] + sb1) = pd;
            p += __shfl_xor(p, 1);
            p += __shfl_xor(p, 2);
            p += __shfl_xor(p, 4);
            if (seg == 0) dotv[nxt][str] = p;
        }
        __syncthreads();
        t = tn;
        cur = nxt;
    }
}

extern "C" void kernel_launch(void* const* d_in, const int* in_sizes, int n_in,
                              void* d_out, int out_size, void* d_ws, size_t ws_size,
                              hipStream_t stream) {
    const float* S  = (const float*)d_in[0];
    const float* O  = (const float*)d_in[1];
    const float* Vs = (const float*)d_in[2];
    const float* Vo = (const float*)d_in[3];
    const float* Ws = (const float*)d_in[4];
    const float* Wo = (const float*)d_in[5];
    const float* w  = (const float*)d_in[6];
    float* out = (float*)d_out;
    relup_kernel<<<NBLOCKS, NTHREADS, 0, stream>>>(S, O, Vs, Vo, Ws, Wo, w, out);
}

// Round 5
// 303.323 us; speedup vs baseline: 1.0781x; 1.0781x over previous
//
#include <hip/hip_runtime.h>
#include <hip/hip_bf16.h>

#define BR_N     1000000
#define DIM      128
#define TILE_M   64
#define NTILES   (BR_N / TILE_M)   /* 15625, exact */
#define NTHREADS 512
#define NBLOCKS  512               /* = prefetch stride G */
#define TBYTES   (TILE_M * 256)    /* one bf16 tile: 64 rows x 256 B */

typedef __attribute__((ext_vector_type(8))) short    bf16x8;
typedef __attribute__((ext_vector_type(4))) float    f32x4;
typedef __attribute__((ext_vector_type(4))) unsigned u32x4;
typedef __attribute__((ext_vector_type(2))) unsigned u32x2;

// f32 pair -> packed bf16x2 (RNE) via v_cvt_pk_bf16_f32
static __device__ __forceinline__ unsigned pk2(float a, float b) {
    union { __hip_bfloat162 h; unsigned u; } v;
    v.h = __float22bfloat162_rn(float2{a, b});
    return v.u;
}

union FragU { bf16x8 v; u32x4 u; };

static __device__ __forceinline__ bf16x8 cvt8(const f32x4 a, const f32x4 b) {
    FragU r;
    r.u.x = pk2(a.x, a.y);
    r.u.y = pk2(a.z, a.w);
    r.u.z = pk2(b.x, b.y);
    r.u.w = pk2(b.z, b.w);
    return r.v;
}

static __device__ __forceinline__ float bf2f(unsigned short b) {
    union { unsigned u; float f; } v;
    v.u = ((unsigned)b) << 16;
    return v.f;
}

// Writer-side LDS flush + RAW barrier. Deliberately NOT __syncthreads():
// __syncthreads drains vmcnt(0), which would kill the distance-2 in-flight
// global loads (m97 barrier-drain finding; m201 verified raw s_barrier keeps
// loads in flight). "memory" clobbers pin ds ops on both sides.
static __device__ __forceinline__ void tile_barrier() {
    asm volatile("s_waitcnt lgkmcnt(0)" ::: "memory");
    __builtin_amdgcn_s_barrier();
    asm volatile("" ::: "memory");
}

// out = sigmoid(s@Vs.T + o@Vo.T) * relu(s@Ws.T + o@Wo.T + s*(o.w))
//
// Distance-2 register prefetch: two tile register sets (A/B). Iteration m:
// issue loads for tile t+2G into the set freed last iteration, MFMA tile t
// from LDS[cur], pack tile t+G (loaded one FULL iteration ago -> HBM latency
// + queue time covered), raw-barrier. launch_bounds(512,2) -> VGPR cap 256,
// 1 block/CU (compute ~1.5k cy/tile vs ~9.4k cy HBM service -> 8 waves ok).
__global__ __launch_bounds__(NTHREADS, 2)
void relup_kernel(const float* __restrict__ S, const float* __restrict__ O,
                  const float* __restrict__ Vs, const float* __restrict__ Vo,
                  const float* __restrict__ Ws, const float* __restrict__ Wo,
                  const float* __restrict__ W1, float* __restrict__ out)
{
    // double-buffered bf16 tiles, row stride 256 B, byte-swizzled:
    // 16B granule g of row r lives at (g ^ (r&7))
    __shared__ __align__(16) unsigned char sT[2][TBYTES];
    __shared__ __align__(16) unsigned char oT[2][TBYTES];
    __shared__ float dotv[2][TILE_M];

    const int tid  = threadIdx.x;
    const int lane = tid & 63;
    const int wv   = tid >> 6;       // wave id 0..7, owns output features [wv*16, wv*16+16)
    const int c0   = wv << 4;

    // ---- preload weight fragments into registers (held for whole kernel) ----
    // lane holds W[c0+(lane&15)][kk*32 + (lane>>4)*8 + j] — used as MFMA A operand
    bf16x8 fVs[4], fVo[4], fWs[4], fWo[4];
    {
        const int wr = c0 + (lane & 15);
        const int wc = (lane >> 4) << 3;
        #pragma unroll
        for (int kk = 0; kk < 4; ++kk) {
            const int off = wr * DIM + kk * 32 + wc;
            fVs[kk] = cvt8(*(const f32x4*)(Vs + off), *(const f32x4*)(Vs + off + 4));
            fVo[kk] = cvt8(*(const f32x4*)(Vo + off), *(const f32x4*)(Vo + off + 4));
            fWs[kk] = cvt8(*(const f32x4*)(Ws + off), *(const f32x4*)(Ws + off + 4));
            fWo[kk] = cvt8(*(const f32x4*)(Wo + off), *(const f32x4*)(Wo + off + 4));
        }
    }

    // staging assignment: thread -> (row 0..63, 16-float segment 0..7)
    const int str = tid >> 3;
    const int seg = tid & 7;
    const int swS = (str & 7) << 4;
    const int sb0 = str * 256 + ((seg * 32) ^ swS);
    const int sb1 = str * 256 + (((seg * 32) + 16) ^ swS);

    // w segment held in registers (keeps the pack phase load-free)
    const float* wp = W1 + seg * 16;
    const f32x4 wq0 = ((const f32x4*)wp)[0], wq1 = ((const f32x4*)wp)[1];
    const f32x4 wq2 = ((const f32x4*)wp)[2], wq3 = ((const f32x4*)wp)[3];

    // two register tile sets
    f32x4 As0, As1, As2, As3, Ao0, Ao1, Ao2, Ao3;
    f32x4 Bs0, Bs1, Bs2, Bs3, Bo0, Bo1, Bo2, Bo3;

#define ISSUE(tIdx, Rs0,Rs1,Rs2,Rs3, Ro0,Ro1,Ro2,Ro3) do {                 \
        const float* sp_ = S + ((tIdx) * TILE_M + str) * DIM + seg * 16;   \
        const float* op_ = O + ((tIdx) * TILE_M + str) * DIM + seg * 16;   \
        Rs0 = ((const f32x4*)sp_)[0]; Rs1 = ((const f32x4*)sp_)[1];        \
        Rs2 = ((const f32x4*)sp_)[2]; Rs3 = ((const f32x4*)sp_)[3];        \
        Ro0 = ((const f32x4*)op_)[0]; Ro1 = ((const f32x4*)op_)[1];        \
        Ro2 = ((const f32x4*)op_)[2]; Ro3 = ((const f32x4*)op_)[3];        \
    } while (0)

#define PACK(buf, Rs0,Rs1,Rs2,Rs3, Ro0,Ro1,Ro2,Ro3) do {                               \
        float p_ = Ro0.x*wq0.x + Ro0.y*wq0.y + Ro0.z*wq0.z + Ro0.w*wq0.w               \
                 + Ro1.x*wq1.x + Ro1.y*wq1.y + Ro1.z*wq1.z + Ro1.w*wq1.w               \
                 + Ro2.x*wq2.x + Ro2.y*wq2.y + Ro2.z*wq2.z + Ro2.w*wq2.w               \
                 + Ro3.x*wq3.x + Ro3.y*wq3.y + Ro3.z*wq3.z + Ro3.w*wq3.w;              \
        u32x4 pa_ = { pk2(Rs0.x,Rs0.y), pk2(Rs0.z,Rs0.w), pk2(Rs1.x,Rs1.y), pk2(Rs1.z,Rs1.w) }; \
        u32x4 pb_ = { pk2(Rs2.x,Rs2.y), pk2(Rs2.z,Rs2.w), pk2(Rs3.x,Rs3.y), pk2(Rs3.z,Rs3.w) }; \
        u32x4 pc_ = { pk2(Ro0.x,Ro0.y), pk2(Ro0.z,Ro0.w), pk2(Ro1.x,Ro1.y), pk2(Ro1.z,Ro1.w) }; \
        u32x4 pd_ = { pk2(Ro2.x,Ro2.y), pk2(Ro2.z,Ro2.w), pk2(Ro3.x,Ro3.y), pk2(Ro3.z,Ro3.w) }; \
        *(u32x4*)(sT[buf] + sb0) = pa_;                                                \
        *(u32x4*)(sT[buf] + sb1) = pb_;                                                \
        *(u32x4*)(oT[buf] + sb0) = pc_;                                                \
        *(u32x4*)(oT[buf] + sb1) = pd_;                                                \
        p_ += __shfl_xor(p_, 1);                                                       \
        p_ += __shfl_xor(p_, 2);                                                       \
        p_ += __shfl_xor(p_, 4);                                                       \
        if (seg == 0) dotv[buf][str] = p_;                                             \
    } while (0)

#define COMPUTE(tIdx, buf) do {                                                        \
        const int row0_ = (tIdx) * TILE_M;                                             \
        const unsigned char* sTc_ = sT[buf];                                           \
        const unsigned char* oTc_ = oT[buf];                                           \
        const float* dvc_ = dotv[buf];                                                 \
        _Pragma("unroll")                                                              \
        for (int b = 0; b < 4; ++b) {                                                  \
            const int r0_  = b << 4;                                                   \
            const int ar_  = r0_ + (lane & 15);                                        \
            const int swA_ = (ar_ & 7) << 4;                                           \
            const int acb_ = (lane >> 4) << 4;                                         \
            bf16x8 fs_[4], fo_[4];                                                     \
            _Pragma("unroll")                                                          \
            for (int kk = 0; kk < 4; ++kk) {                                           \
                const int cb_ = ((kk << 6) + acb_) ^ swA_;                             \
                fs_[kk] = *(const bf16x8*)(sTc_ + ar_ * 256 + cb_);                    \
                fo_[kk] = *(const bf16x8*)(oTc_ + ar_ * 256 + cb_);                    \
            }                                                                          \
            f32x4 accg_ = {0.f, 0.f, 0.f, 0.f};                                        \
            f32x4 accd_ = {0.f, 0.f, 0.f, 0.f};                                        \
            _Pragma("unroll")                                                          \
            for (int kk = 0; kk < 4; ++kk) {                                           \
                accg_ = __builtin_amdgcn_mfma_f32_16x16x32_bf16(fVs[kk], fs_[kk], accg_, 0, 0, 0); \
                accg_ = __builtin_amdgcn_mfma_f32_16x16x32_bf16(fVo[kk], fo_[kk], accg_, 0, 0, 0); \
                accd_ = __builtin_amdgcn_mfma_f32_16x16x32_bf16(fWs[kk], fs_[kk], accd_, 0, 0, 0); \
                accd_ = __builtin_amdgcn_mfma_f32_16x16x32_bf16(fWo[kk], fo_[kk], accd_, 0, 0, 0); \
            }                                                                          \
            /* swapped C/D: lane -> batch row r0+(lane&15), features f0..f0+3 */       \
            const int row_ = r0_ + (lane & 15);                                        \
            const int f0_  = c0 + ((lane >> 4) << 2);                                  \
            const float dv_ = dvc_[row_];                                              \
            const int sOff_ = row_ * 256 + ((2 * f0_) ^ ((row_ & 7) << 4));            \
            const u32x2 sv_ = *(const u32x2*)(sTc_ + sOff_);                           \
            const float sq0_ = bf2f((unsigned short)(sv_.x & 0xffffu));                \
            const float sq1_ = bf2f((unsigned short)(sv_.x >> 16));                    \
            const float sq2_ = bf2f((unsigned short)(sv_.y & 0xffffu));                \
            const float sq3_ = bf2f((unsigned short)(sv_.y >> 16));                    \
            f32x4 res_;                                                                \
            {                                                                          \
                const float g0_ = 1.0f / (1.0f + __expf(-accg_[0]));                   \
                const float g1_ = 1.0f / (1.0f + __expf(-accg_[1]));                   \
                const float g2_ = 1.0f / (1.0f + __expf(-accg_[2]));                   \
                const float g3_ = 1.0f / (1.0f + __expf(-accg_[3]));                   \
                float d0_ = accd_[0] + sq0_ * dv_; d0_ = d0_ > 0.f ? d0_ : 0.f;        \
                float d1_ = accd_[1] + sq1_ * dv_; d1_ = d1_ > 0.f ? d1_ : 0.f;        \
                float d2_ = accd_[2] + sq2_ * dv_; d2_ = d2_ > 0.f ? d2_ : 0.f;        \
                float d3_ = accd_[3] + sq3_ * dv_; d3_ = d3_ > 0.f ? d3_ : 0.f;        \
                res_.x = g0_ * d0_; res_.y = g1_ * d1_;                                \
                res_.z = g2_ * d2_; res_.w = g3_ * d3_;                                \
            }                                                                          \
            *(f32x4*)(out + (row0_ + row_) * DIM + f0_) = res_;                        \
        }                                                                              \
    } while (0)

    int t = blockIdx.x;

    // ---- prologue: A <- tile t, B <- tile t+G (clamped); pack A -> buf0 ----
    ISSUE(t, As0,As1,As2,As3, Ao0,Ao1,Ao2,Ao3);
    {
        int tB = t + NBLOCKS; if (tB >= NTILES) tB = t;   // clamp: never packed if OOB
        ISSUE(tB, Bs0,Bs1,Bs2,Bs3, Bo0,Bo1,Bo2,Bo3);
    }
    PACK(0, As0,As1,As2,As3, Ao0,Ao1,Ao2,Ao3);
    tile_barrier();

    int cur = 0;
    for (;;) {
        // ---- even body: compute t from buf[cur]; pack B; refill A with t+2G ----
        {
            const bool more1 = (t + NBLOCKS)     < NTILES;
            const bool more2 = (t + 2 * NBLOCKS) < NTILES;
            if (more2) ISSUE(t + 2 * NBLOCKS, As0,As1,As2,As3, Ao0,Ao1,Ao2,Ao3);
            COMPUTE(t, cur);
            if (!more1) break;
            PACK(cur ^ 1, Bs0,Bs1,Bs2,Bs3, Bo0,Bo1,Bo2,Bo3);
            tile_barrier();
            cur ^= 1; t += NBLOCKS;
        }
        // ---- odd body: compute t from buf[cur]; pack A; refill B with t+2G ----
        {
            const bool more1 = (t + NBLOCKS)     < NTILES;
            const bool more2 = (t + 2 * NBLOCKS) < NTILES;
            if (more2) ISSUE(t + 2 * NBLOCKS, Bs0,Bs1,Bs2,Bs3, Bo0,Bo1,Bo2,Bo3);
            COMPUTE(t, cur);
            if (!more1) break;
            PACK(cur ^ 1, As0,As1,As2,As3, Ao0,Ao1,Ao2,Ao3);
            tile_barrier();
            cur ^= 1; t += NBLOCKS;
        }
    }
#undef ISSUE
#undef PACK
#undef COMPUTE
}

extern "C" void kernel_launch(void* const* d_in, const int* in_sizes, int n_in,
                              void* d_out, int out_size, void* d_ws, size_t ws_size,
                              hipStream_t stream) {
    const float* S  = (const float*)d_in[0];
    const float* O  = (const float*)d_in[1];
    const float* Vs = (const float*)d_in[2];
    const float* Vo = (const float*)d_in[3];
    const float* Ws = (const float*)d_in[4];
    const float* Wo = (const float*)d_in[5];
    const float* w  = (const float*)d_in[6];
    float* out = (float*)d_out;
    relup_kernel<<<NBLOCKS, NTHREADS, 0, stream>>>(S, O, Vs, Vo, Ws, Wo, w, out);
}